// Round 15
// baseline (175.205 us; speedup 1.0000x reference)
//
#include <hip/hip_runtime.h>
#include <stdint.h>

typedef __attribute__((ext_vector_type(8))) short short8;
typedef __attribute__((ext_vector_type(4))) float f32x4;
typedef __attribute__((ext_vector_type(4))) int int32x4;
typedef unsigned short ushort_t;
typedef signed char i8_t;

#define SEQ   2048
#define BSZ   2
#define DIM   1024
#define NHEAD 16
#define HDIM  64
#define MROWS (BSZ*SEQ)   // 4096

__device__ __forceinline__ ushort_t f2bf(float f) {
  unsigned u = __float_as_uint(f);
  unsigned r = u + 0x7fffu + ((u >> 16) & 1u);
  return (ushort_t)(r >> 16);
}
__device__ __forceinline__ float bf2f(ushort_t u) {
  return __uint_as_float(((unsigned)u) << 16);
}

__device__ __forceinline__ unsigned cvt_pk_bf16(float lo, float hi) {
  unsigned r;
  asm("v_cvt_pk_bf16_f32 %0, %1, %2" : "=v"(r) : "v"(lo), "v"(hi));
  return r;
}

__device__ __forceinline__ float fast_exp2(float x) {
#if __has_builtin(__builtin_amdgcn_exp2f)
  return __builtin_amdgcn_exp2f(x);
#else
  return exp2f(x);
#endif
}

__device__ __forceinline__ int pack4i8(float a, float b, float c, float d) {
  int ia = (int)rintf(a), ib = (int)rintf(b), ic = (int)rintf(c), id = (int)rintf(d);
  return (ia & 255) | ((ib & 255) << 8) | ((ic & 255) << 16) | (id << 24);
}

// async global->LDS, 16B/lane, wave-uniform LDS base + lane*16 (linear dest).
typedef __attribute__((address_space(1))) void gas_void;
typedef __attribute__((address_space(3))) void las_void;
__device__ __forceinline__ void gll16(const void* g, void* l, int lane) {
#if __has_builtin(__builtin_amdgcn_global_load_lds)
  __builtin_amdgcn_global_load_lds((gas_void*)g, (las_void*)l, 16, 0, 0);
#else
  ((int4*)l)[lane] = *(const int4*)g;
#endif
}

// ---------------- amax: x + 4 weights in one dispatch ----------------
__device__ __forceinline__ void amax_reduce_store(float m, unsigned* slot) {
  __shared__ float wred[4];
  int wv = threadIdx.x >> 6, lane = threadIdx.x & 63;
#pragma unroll
  for (int off = 32; off > 0; off >>= 1) m = fmaxf(m, __shfl_down(m, off));
  if (lane == 0) wred[wv] = m;
  __syncthreads();
  if (threadIdx.x == 0) {
    float r = fmaxf(fmaxf(wred[0], wred[1]), fmaxf(wred[2], wred[3]));
    atomicMax(slot, __float_as_uint(r));
  }
}

__global__ __launch_bounds__(256) void amax5_kernel(
    const float* __restrict__ x, const float* w0, const float* w1,
    const float* w2, const float* w3, int n4x, int n4w,
    unsigned* __restrict__ slots) {
  int y = blockIdx.y;
  const float* p = (y == 0) ? x : (y == 1) ? w0 : (y == 2) ? w1 : (y == 3) ? w2 : w3;
  int n4 = (y == 0) ? n4x : n4w;
  const float4* x4 = (const float4*)p;
  float m = 0.f;
  for (int i = blockIdx.x * blockDim.x + threadIdx.x; i < n4; i += gridDim.x * blockDim.x) {
    float4 v = x4[i];
    m = fmaxf(m, fmaxf(fmaxf(fabsf(v.x), fabsf(v.y)), fmaxf(fabsf(v.z), fabsf(v.w))));
  }
  amax_reduce_store(m, slots + y);
}

// ------- fused prep: 4 rows/block act-quant + LoRA-t, weight-quant tail -------
__global__ __launch_bounds__(256) void prep_kernel(
    const float* __restrict__ x, const unsigned* __restrict__ slots,
    i8_t* __restrict__ xc,
    const float* __restrict__ A0, const float* __restrict__ A1, const float* __restrict__ A2,
    float* __restrict__ t0, float* __restrict__ t1, float* __restrict__ t2,
    const float* w0, const float* w1, const float* w2, const float* w3,
    i8_t* q0, i8_t* q1, i8_t* q2, i8_t* q3, int n4w) {
  const int tid = threadIdx.x;
  if ((int)blockIdx.x >= MROWS / 4) {
    int wb = blockIdx.x - MROWS / 4;
    int y = wb >> 7, bx = wb & 127;
    const float* wsrc = (y == 0) ? w0 : (y == 1) ? w1 : (y == 2) ? w2 : w3;
    i8_t* qc = (y == 0) ? q0 : (y == 1) ? q1 : (y == 2) ? q2 : q3;
    float amax = __uint_as_float(slots[y + 1]);
    float inv = 1.0f / fmaxf(amax / 127.0f, 1e-8f);
    const float4* x4 = (const float4*)wsrc;
    int* q4 = (int*)qc;
    for (int i = bx * 256 + tid; i < n4w; i += 128 * 256) {
      float4 v = x4[i];
      q4[i] = pack4i8(v.x * inv, v.y * inv, v.z * inv, v.w * inv);
    }
    return;
  }
  const int row0 = blockIdx.x * 4;
  const int k0 = tid * 4;
  float amax = __uint_as_float(slots[0]);
  float inv = 1.0f / fmaxf(amax / 127.0f, 1e-8f);

  float4 xv[4];
#pragma unroll
  for (int rr = 0; rr < 4; rr++) {
    xv[rr] = *(const float4*)&x[(size_t)(row0 + rr) * DIM + k0];
    *(int*)&xc[(size_t)(row0 + rr) * DIM + k0] =
        pack4i8(xv[rr].x * inv, xv[rr].y * inv, xv[rr].z * inv, xv[rr].w * inv);
  }

  float p[4][24];
#pragma unroll
  for (int r = 0; r < 8; r++) {
    float4 a0 = *(const float4*)&A0[r * DIM + k0];
    float4 a1 = *(const float4*)&A1[r * DIM + k0];
    float4 a2 = *(const float4*)&A2[r * DIM + k0];
#pragma unroll
    for (int rr = 0; rr < 4; rr++) {
      p[rr][r]      = xv[rr].x * a0.x + xv[rr].y * a0.y + xv[rr].z * a0.z + xv[rr].w * a0.w;
      p[rr][8 + r]  = xv[rr].x * a1.x + xv[rr].y * a1.y + xv[rr].z * a1.z + xv[rr].w * a1.w;
      p[rr][16 + r] = xv[rr].x * a2.x + xv[rr].y * a2.y + xv[rr].z * a2.z + xv[rr].w * a2.w;
    }
  }
#pragma unroll
  for (int rr = 0; rr < 4; rr++)
#pragma unroll
    for (int j = 0; j < 24; j++) {
      float v = p[rr][j];
#pragma unroll
      for (int off = 32; off > 0; off >>= 1) v += __shfl_down(v, off);
      p[rr][j] = v;
    }
  __shared__ float red[4][4][24];
  int wv = tid >> 6, lane = tid & 63;
  if (lane == 0) {
#pragma unroll
    for (int rr = 0; rr < 4; rr++)
#pragma unroll
      for (int j = 0; j < 24; j++) red[wv][rr][j] = p[rr][j];
  }
  __syncthreads();
  if (tid < 96) {
    int rr = tid / 24, j = tid - rr * 24;
    float sv = red[0][rr][j] + red[1][rr][j] + red[2][rr][j] + red[3][rr][j];
    float* tp = (j < 8) ? t0 : ((j < 16) ? t1 : t2);
    tp[(size_t)(row0 + rr) * 8 + (j & 7)] = sv;
  }
}

// ------- act-quant + LoRA-t for attn output (bf16 input), 4 rows/block -------
__global__ __launch_bounds__(256) void lora_quant1_kernel(
    const ushort_t* __restrict__ x, const unsigned* __restrict__ slot,
    i8_t* __restrict__ xc, const float* __restrict__ A0, float* __restrict__ t0) {
  const int row0 = blockIdx.x * 4;
  const int tid = threadIdx.x;
  const int k0 = tid * 4;
  float amax = __uint_as_float(*slot);
  float inv = 1.0f / fmaxf(amax / 127.0f, 1e-8f);

  float4 xv[4];
#pragma unroll
  for (int rr = 0; rr < 4; rr++) {
    ushort4 xu = *(const ushort4*)&x[(size_t)(row0 + rr) * DIM + k0];
    xv[rr].x = bf2f(xu.x); xv[rr].y = bf2f(xu.y); xv[rr].z = bf2f(xu.z); xv[rr].w = bf2f(xu.w);
    *(int*)&xc[(size_t)(row0 + rr) * DIM + k0] =
        pack4i8(xv[rr].x * inv, xv[rr].y * inv, xv[rr].z * inv, xv[rr].w * inv);
  }

  float p[4][8];
#pragma unroll
  for (int r = 0; r < 8; r++) {
    float4 a = *(const float4*)&A0[r * DIM + k0];
#pragma unroll
    for (int rr = 0; rr < 4; rr++)
      p[rr][r] = xv[rr].x * a.x + xv[rr].y * a.y + xv[rr].z * a.z + xv[rr].w * a.w;
  }
#pragma unroll
  for (int rr = 0; rr < 4; rr++)
#pragma unroll
    for (int j = 0; j < 8; j++) {
      float v = p[rr][j];
#pragma unroll
      for (int off = 32; off > 0; off >>= 1) v += __shfl_down(v, off);
      p[rr][j] = v;
    }
  __shared__ float red[4][4][8];
  int wv = tid >> 6, lane = tid & 63;
  if (lane == 0) {
#pragma unroll
    for (int rr = 0; rr < 4; rr++)
#pragma unroll
      for (int j = 0; j < 8; j++) red[wv][rr][j] = p[rr][j];
  }
  __syncthreads();
  if (tid < 32) {
    int rr = tid >> 3, j = tid & 7;
    t0[(size_t)(row0 + rr) * 8 + j] =
        red[0][rr][j] + red[1][rr][j] + red[2][rr][j] + red[3][rr][j];
  }
}

// ------- projection GEMM on int8 codes via mfma_i32_16x16x64_i8 (exact) -------
template <bool BF16OUT, int BN, bool CANTRANS>
__device__ __forceinline__ void proj_body(
    const i8_t* __restrict__ Ac, const i8_t* __restrict__ Wc,
    const unsigned* __restrict__ sxslot, const unsigned* __restrict__ swslot,
    const float* __restrict__ bias, const float* __restrict__ t,
    const float* __restrict__ Bl, void* __restrict__ Cout,
    ushort_t* __restrict__ vTout, int m0, int n0) {
  constexpr int CODEB = 128 * 128 + BN * 128;
  constexpr int T2B = CANTRANS ? 128 * 136 * 2 : 0;
  constexpr int BASE = (T2B > CODEB) ? T2B : CODEB;
  __shared__ alignas(16) char smem[BASE + 128 * 32 + BN * 32 + BN * 4];
  i8_t* Asb = (i8_t*)smem;
  i8_t* Bsb = (i8_t*)(smem + 128 * 128);
  ushort_t* T2 = (ushort_t*)smem;
  float* Ts = (float*)(smem + BASE);
  float* Bls = Ts + 128 * 8;
  float* biass = Bls + BN * 8;

  const int tid = threadIdx.x;
  constexpr int NJ = BN / 32;
  constexpr int BITS = BN / 32;

  for (int i = tid; i < 128 * 8; i += 256) Ts[i] = t[(size_t)m0 * 8 + i];
  for (int i = tid; i < BN * 8; i += 256) Bls[i] = Bl[(size_t)n0 * 8 + i];
  if (tid < BN) biass[tid] = bias[n0 + tid];

  int32x4 acc[4][NJ];
#pragma unroll
  for (int i = 0; i < 4; i++)
#pragma unroll
    for (int j = 0; j < NJ; j++) {
      acc[i][j][0] = 0; acc[i][j][1] = 0; acc[i][j][2] = 0; acc[i][j][3] = 0;
    }

  const int wv = tid >> 6, lane = tid & 63;
  const int wr = wv >> 1, wc = wv & 1;
  const int l15 = lane & 15, hi = lane >> 4;
  const int lr8 = lane >> 3, lc8 = lane & 7;

  for (int kt = 0; kt < 8; kt++) {
    const int k0 = kt * 128;
#pragma unroll
    for (int j = 0; j < 4; j++) {
      int row = wv * 32 + j * 8 + lr8;
      int cs = lc8 ^ (row & 7);
      gll16(&Ac[(size_t)(m0 + row) * DIM + k0 + cs * 16], &Asb[(wv * 32 + j * 8) * 128], lane);
    }
#pragma unroll
    for (int j = 0; j < BITS; j++) {
      int row = wv * (BN / 4) + j * 8 + lr8;
      int cs = lc8 ^ (row & 7);
      gll16(&Wc[(size_t)(n0 + row) * DIM + k0 + cs * 16], &Bsb[(wv * (BN / 4) + j * 8) * 128], lane);
    }
    __syncthreads();
#pragma unroll
    for (int ks = 0; ks < 2; ks++) {
      int32x4 a[4], b[NJ];
#pragma unroll
      for (int i = 0; i < 4; i++) {
        int row = wr * 64 + i * 16 + l15;
        a[i] = *(const int32x4*)&Asb[row * 128 + (((ks * 4 + hi) ^ (row & 7))) * 16];
      }
#pragma unroll
      for (int j = 0; j < NJ; j++) {
        int col = wc * (BN / 2) + j * 16 + l15;
        b[j] = *(const int32x4*)&Bsb[col * 128 + (((ks * 4 + hi) ^ (col & 7))) * 16];
      }
      __builtin_amdgcn_s_setprio(1);
#pragma unroll
      for (int i = 0; i < 4; i++)
#pragma unroll
        for (int j = 0; j < NJ; j++)
          acc[i][j] = __builtin_amdgcn_mfma_i32_16x16x64_i8(a[i], b[j], acc[i][j], 0, 0, 0);
      __builtin_amdgcn_s_setprio(0);
    }
    __syncthreads();
  }

  float sx = fmaxf(__uint_as_float(*sxslot) / 127.0f, 1e-8f);
  float sw = fmaxf(__uint_as_float(*swslot) / 127.0f, 1e-8f);
  float ss = sx * sw;

  if (CANTRANS && vTout != nullptr) {
#pragma unroll
    for (int i = 0; i < 4; i++) {
      int rl0 = wr * 64 + i * 16 + hi * 4;
      float tv[4][8];
#pragma unroll
      for (int rr = 0; rr < 4; rr++)
#pragma unroll
        for (int q = 0; q < 8; q++) tv[rr][q] = Ts[(rl0 + rr) * 8 + q];
#pragma unroll
      for (int j = 0; j < NJ; j++) {
        int cl = wc * (BN / 2) + j * 16 + l15;
        float val[4];
#pragma unroll
        for (int rr = 0; rr < 4; rr++) {
          float lr = 0.f;
#pragma unroll
          for (int q = 0; q < 8; q++) lr += tv[rr][q] * Bls[cl * 8 + q];
          val[rr] = (float)acc[i][j][rr] * ss + biass[cl] + 2.0f * lr;
        }
        unsigned w0 = cvt_pk_bf16(val[0], val[1]);
        unsigned w1 = cvt_pk_bf16(val[2], val[3]);
        *(uint2*)&T2[cl * 136 + rl0] = make_uint2(w0, w1);
      }
    }
    __syncthreads();
    const int bb = m0 >> 11;
    const int sbase = m0 & 2047;
#pragma unroll
    for (int it = 0; it < 8; it++) {
      int g = it * 256 + tid;
      int d = g >> 4, c = g & 15;
      int gdim = n0 + d;
      int hh = gdim >> 6, dd = gdim & 63;
      int bh = bb * 16 + hh;
      int4 v = *(const int4*)&T2[d * 136 + c * 8];
      *(int4*)&vTout[((size_t)(bh * 64 + dd)) * SEQ + sbase + c * 8] = v;
    }
    return;
  }

#pragma unroll
  for (int i = 0; i < 4; i++) {
#pragma unroll
    for (int rr = 0; rr < 4; rr++) {
      int rl = wr * 64 + i * 16 + hi * 4 + rr;
      float tv[8];
#pragma unroll
      for (int q = 0; q < 8; q++) tv[q] = Ts[rl * 8 + q];
#pragma unroll
      for (int j = 0; j < NJ; j++) {
        int cl = wc * (BN / 2) + j * 16 + l15;
        float lr = 0.f;
#pragma unroll
        for (int q = 0; q < 8; q++) lr += tv[q] * Bls[cl * 8 + q];
        float val = (float)acc[i][j][rr] * ss + biass[cl] + 2.0f * lr;
        if (BF16OUT)
          ((ushort_t*)Cout)[(size_t)(m0 + rl) * DIM + n0 + cl] = f2bf(val);
        else
          ((float*)Cout)[(size_t)(m0 + rl) * DIM + n0 + cl] = val;
      }
    }
  }
}

struct ProjSet {
  const i8_t* W; const unsigned* sw; const float* bias;
  const float* t; const float* Bl; ushort_t* out;
};

__global__ __launch_bounds__(256) void proj_qkv_kernel(
    const i8_t* __restrict__ Ac, const unsigned* __restrict__ sxslot,
    ProjSet pq, ProjSet pk, ProjSet pv, ushort_t* __restrict__ vT) {
  ProjSet P = (blockIdx.z == 0) ? pq : (blockIdx.z == 1) ? pk : pv;
  ushort_t* vt = (blockIdx.z == 2) ? vT : nullptr;
  proj_body<true, 128, true>(Ac, P.W, sxslot, P.sw, P.bias, P.t, P.Bl, P.out,
                             vt, blockIdx.y * 128, blockIdx.x * 128);
}

__global__ __launch_bounds__(256) void proj_out_kernel(
    const i8_t* __restrict__ Ac, const i8_t* __restrict__ Wc,
    const unsigned* __restrict__ sxslot, const unsigned* __restrict__ swslot,
    const float* __restrict__ bias, const float* __restrict__ t,
    const float* __restrict__ Bl, float* __restrict__ Cout) {
  proj_body<false, 64, false>(Ac, Wc, sxslot, swslot, bias, t, Bl, Cout,
                              nullptr, blockIdx.y * 128, blockIdx.x * 64);
}

// ------- flash attention v10 (proven 65.3us): 8 waves / 512 threads -------
__global__ __launch_bounds__(512) void attn10_kernel(
    const ushort_t* __restrict__ qb, const ushort_t* __restrict__ kb,
    const ushort_t* __restrict__ vT, const float* __restrict__ mask,
    ushort_t* __restrict__ obuf, unsigned* __restrict__ amax_slot) {
  __shared__ alignas(16) ushort_t Ks[2][64 * 64];
  __shared__ alignas(16) ushort_t Vs[2][64 * 64];   // Vs[d][key]
  __shared__ alignas(16) ushort_t Ps[128 * 72];
  __shared__ alignas(16) float maskv[2][64];
  __shared__ float wmax[8];

  const float LOG2E = 1.44269504088896f;
  const float SCL2 = 0.125f * LOG2E;
  const float THR2 = 8.0f * LOG2E;

  const int lin = blockIdx.x;
  const int logical = (lin & 7) * 64 + (lin >> 3);
  const int bh = logical >> 4;
  const int qt = logical & 15;
  const int b = bh >> 4, h = bh & 15;
  const size_t tokbase = (size_t)b * SEQ;
  const int q0 = qt * 128;

  const int tid = threadIdx.x;
  const int wv = tid >> 6, lane = tid & 63, l15 = lane & 15, hi = lane >> 4;
  const int sr = tid >> 3, sc = tid & 7;
  const int sslot = (sc ^ (sr & 7)) * 8;

  short8 qf[2];
#pragma unroll
  for (int ks = 0; ks < 2; ks++) {
    int row = q0 + wv * 16 + l15;
    qf[ks] = *(const short8*)&qb[(tokbase + row) * DIM + h * 64 + ks * 32 + hi * 8];
  }

  float mo = -1e30f, ls = 0.f;
  f32x4 o[4];
#pragma unroll
  for (int d = 0; d < 4; d++) { o[d][0] = 0.f; o[d][1] = 0.f; o[d][2] = 0.f; o[d][3] = 0.f; }

  int4 kpre, vpre;
  float mpre;
  kpre = *(const int4*)&kb[(tokbase + sr) * DIM + h * 64 + sc * 8];
  vpre = *(const int4*)&vT[((size_t)bh * 64 + sr) * SEQ + sc * 8];
  mpre = (tid < 64) ? (1.0f - mask[tokbase + tid]) * (-10000.0f * LOG2E) : 0.f;
  *(int4*)&Ks[0][sr * 64 + sslot] = kpre;
  *(int4*)&Vs[0][sr * 64 + sslot] = vpre;
  if (tid < 64) maskv[0][tid] = mpre;
  __syncthreads();

  for (int kt = 0; kt < 32; kt++) {
    const int cur = kt & 1, nxt = cur ^ 1;

    if (kt < 31) {
      const int k0n = (kt + 1) * 64;
      kpre = *(const int4*)&kb[(tokbase + k0n + sr) * DIM + h * 64 + sc * 8];
      vpre = *(const int4*)&vT[((size_t)bh * 64 + sr) * SEQ + k0n + sc * 8];
      if (tid < 64) mpre = (1.0f - mask[tokbase + k0n + tid]) * (-10000.0f * LOG2E);
    }

    f32x4 s2[4];
#pragma unroll
    for (int kb4 = 0; kb4 < 4; kb4++) { s2[kb4][0] = 0.f; s2[kb4][1] = 0.f; s2[kb4][2] = 0.f; s2[kb4][3] = 0.f; }
#pragma unroll
    for (int ks = 0; ks < 2; ks++) {
      short8 kf[4];
#pragma unroll
      for (int kb4 = 0; kb4 < 4; kb4++) {
        int row = kb4 * 16 + l15;
        kf[kb4] = *(const short8*)&Ks[cur][row * 64 + (((ks * 4 + hi) ^ (row & 7))) * 8];
      }
      __builtin_amdgcn_s_setprio(1);
#pragma unroll
      for (int kb4 = 0; kb4 < 4; kb4++)
        s2[kb4] = __builtin_amdgcn_mfma_f32_16x16x32_bf16(kf[kb4], qf[ks], s2[kb4], 0, 0, 0);
      __builtin_amdgcn_s_setprio(0);
    }

#pragma unroll
    for (int kb4 = 0; kb4 < 4; kb4++) {
      f32x4 mkv = *(const f32x4*)&maskv[cur][kb4 * 16 + hi * 4];
#pragma unroll
      for (int r = 0; r < 4; r++)
        s2[kb4][r] = s2[kb4][r] * SCL2 + mkv[r];
    }

    float t0m = fmaxf(fmaxf(s2[0][0], s2[0][1]), fmaxf(s2[0][2], s2[0][3]));
    float t1m = fmaxf(fmaxf(s2[1][0], s2[1][1]), fmaxf(s2[1][2], s2[1][3]));
    float t2m = fmaxf(fmaxf(s2[2][0], s2[2][1]), fmaxf(s2[2][2], s2[2][3]));
    float t3m = fmaxf(fmaxf(s2[3][0], s2[3][1]), fmaxf(s2[3][2], s2[3][3]));
    float tm = fmaxf(fmaxf(t0m, t1m), fmaxf(t2m, t3m));
    tm = fmaxf(tm, __shfl_xor(tm, 16));
    tm = fmaxf(tm, __shfl_xor(tm, 32));

    bool need = (tm > mo + THR2);
    if (__any(need)) {
      float mn = fmaxf(mo, tm);
      float al = fast_exp2(mo - mn);
      mo = mn;
      ls *= al;
#pragma unroll
      for (int r = 0; r < 4; r++) {
        float ab = __shfl(al, hi * 4 + r);
#pragma unroll
        for (int db = 0; db < 4; db++) o[db][r] *= ab;
      }
    }

    float rsv = 0.f;
#pragma unroll
    for (int kb4 = 0; kb4 < 4; kb4++)
#pragma unroll
      for (int r = 0; r < 4; r++) {
        float pv = fast_exp2(s2[kb4][r] - mo);
        s2[kb4][r] = pv;
        rsv += pv;
      }
    rsv += __shfl_xor(rsv, 16);
    rsv += __shfl_xor(rsv, 32);
    ls += rsv;

    {
      int rowb = (wv * 16 + l15) * 72;
#pragma unroll
      for (int kb4 = 0; kb4 < 4; kb4++) {
        unsigned w0 = cvt_pk_bf16(s2[kb4][0], s2[kb4][1]);
        unsigned w1 = cvt_pk_bf16(s2[kb4][2], s2[kb4][3]);
        *(uint2*)&Ps[rowb + kb4 * 16 + hi * 4] = make_uint2(w0, w1);
      }
    }

#pragma unroll
    for (int ks = 0; ks < 2; ks++) {
      short8 pf = *(const short8*)&Ps[(wv * 16 + l15) * 72 + ks * 32 + hi * 8];
      short8 vf[4];
#pragma unroll
      for (int db = 0; db < 4; db++) {
        int row = db * 16 + l15;
        vf[db] = *(const short8*)&Vs[cur][row * 64 + (((ks * 4 + hi) ^ (row & 7))) * 8];
      }
      __builtin_amdgcn_s_setprio(1);
#pragma unroll
      for (int db = 0; db < 4; db++)
        o[db] = __builtin_amdgcn_mfma_f32_16x16x32_bf16(pf, vf[db], o[db], 0, 0, 0);
      __builtin_amdgcn_s_setprio(0);
    }

    if (kt < 31) {
      *(int4*)&Ks[nxt][sr * 64 + sslot] = kpre;
      *(int4*)&Vs[nxt][sr * 64 + sslot] = vpre;
      if (tid < 64) maskv[nxt][tid] = mpre;
    }
    __syncthreads();
  }

  float am = 0.f;
#pragma unroll
  for (int r = 0; r < 4; r++) {
    float lsb = __shfl(ls, hi * 4 + r);
    float inv = 1.0f / lsb;
    size_t row = tokbase + q0 + wv * 16 + hi * 4 + r;
#pragma unroll
    for (int db = 0; db < 4; db++) {
      float val = o[db][r] * inv;
      ushort_t bv = f2bf(val);
      am = fmaxf(am, fabsf(bf2f(bv)));
      obuf[row * DIM + h * 64 + db * 16 + l15] = bv;
    }
  }
#pragma unroll
  for (int off = 32; off > 0; off >>= 1) am = fmaxf(am, __shfl_down(am, off));
  if (lane == 0) wmax[wv] = am;
  __syncthreads();
  if (tid == 0) {
    float r = wmax[0];
#pragma unroll
    for (int w = 1; w < 8; w++) r = fmaxf(r, wmax[w]);
    atomicMax(amax_slot, __float_as_uint(r));
  }
}

// ---------------- launcher ----------------
extern "C" void kernel_launch(void* const* d_in, const int* in_sizes, int n_in,
                              void* d_out, int out_size, void* d_ws, size_t ws_size,
                              hipStream_t stream) {
  const float* x     = (const float*)d_in[0];
  const float* mask  = (const float*)d_in[1];
  const float* q_W   = (const float*)d_in[2];
  const float* q_b   = (const float*)d_in[3];
  const float* q_A   = (const float*)d_in[4];
  const float* q_B   = (const float*)d_in[5];
  const float* k_W   = (const float*)d_in[6];
  const float* k_b   = (const float*)d_in[7];
  const float* k_A   = (const float*)d_in[8];
  const float* k_B   = (const float*)d_in[9];
  const float* v_W   = (const float*)d_in[10];
  const float* v_b   = (const float*)d_in[11];
  const float* v_A   = (const float*)d_in[12];
  const float* v_B   = (const float*)d_in[13];
  const float* o_W   = (const float*)d_in[14];
  const float* o_b   = (const float*)d_in[15];
  const float* o_A   = (const float*)d_in[16];
  const float* o_B   = (const float*)d_in[17];
  float* out = (float*)d_out;

  char* ws = (char*)d_ws;
  const size_t MB = 1u << 20;
  unsigned* slots = (unsigned*)ws;                  // 6 amax slots
  float* t_q = (float*)(ws + 4096);
  float* t_k = t_q + MROWS * 8;
  float* t_v = t_k + MROWS * 8;
  float* t_o = t_v + MROWS * 8;
  i8_t* xc  = (i8_t*)(ws + 1 * MB);
  i8_t* qWc = (i8_t*)(ws + 9 * MB);
  i8_t* kWc = (i8_t*)(ws + 11 * MB);
  i8_t* vWc = (i8_t*)(ws + 13 * MB);
  i8_t* oWc = (i8_t*)(ws + 15 * MB);
  ushort_t* qbb = (ushort_t*)(ws + 17 * MB);
  ushort_t* kbb = (ushort_t*)(ws + 25 * MB);
  ushort_t* vTb = (ushort_t*)(ws + 41 * MB);
  ushort_t* abuf = (ushort_t*)(ws + 49 * MB);
  i8_t*     ac  = (i8_t*)(ws + 65 * MB);

  (void)hipMemsetAsync(ws, 0, 64, stream);

  const int NX4 = (MROWS * DIM) / 4;
  const int NW4 = (DIM * DIM) / 4;

  amax5_kernel<<<dim3(256, 5), 256, 0, stream>>>(x, q_W, k_W, v_W, o_W, NX4, NW4, slots);

  prep_kernel<<<MROWS / 4 + 512, 256, 0, stream>>>(x, slots, xc, q_A, k_A, v_A,
                                                   t_q, t_k, t_v,
                                                   q_W, k_W, v_W, o_W,
                                                   qWc, kWc, vWc, oWc, NW4);

  ProjSet pq = { qWc, slots + 1, q_b, t_q, q_B, qbb };
  ProjSet pk = { kWc, slots + 2, k_b, t_k, k_B, kbb };
  ProjSet pv = { vWc, slots + 3, v_b, t_v, v_B, nullptr };
  proj_qkv_kernel<<<dim3(DIM / 128, MROWS / 128, 3), 256, 0, stream>>>(
      xc, slots + 0, pq, pk, pv, vTb);

  attn10_kernel<<<512, 512, 0, stream>>>(qbb, kbb, vTb, mask, abuf, slots + 5);

  lora_quant1_kernel<<<MROWS / 4, 256, 0, stream>>>(abuf, slots + 5, ac, o_A, t_o);

  proj_out_kernel<<<dim3(DIM / 64, MROWS / 128), 256, 0, stream>>>(
      ac, oWc, slots + 5, slots + 4, o_b, t_o, o_B, out);
}

// Round 16
// 174.475 us; speedup vs baseline: 1.0042x; 1.0042x over previous
//
#include <hip/hip_runtime.h>
#include <stdint.h>

typedef __attribute__((ext_vector_type(8))) short short8;
typedef __attribute__((ext_vector_type(4))) float f32x4;
typedef __attribute__((ext_vector_type(4))) int int32x4;
typedef unsigned short ushort_t;
typedef signed char i8_t;

#define SEQ   2048
#define BSZ   2
#define DIM   1024
#define NHEAD 16
#define HDIM  64
#define MROWS (BSZ*SEQ)   // 4096

__device__ __forceinline__ ushort_t f2bf(float f) {
  unsigned u = __float_as_uint(f);
  unsigned r = u + 0x7fffu + ((u >> 16) & 1u);
  return (ushort_t)(r >> 16);
}
__device__ __forceinline__ float bf2f(ushort_t u) {
  return __uint_as_float(((unsigned)u) << 16);
}

__device__ __forceinline__ unsigned cvt_pk_bf16(float lo, float hi) {
  unsigned r;
  asm("v_cvt_pk_bf16_f32 %0, %1, %2" : "=v"(r) : "v"(lo), "v"(hi));
  return r;
}
__device__ __forceinline__ float max3f(float a, float b, float c) {
  float d;
  asm("v_max3_f32 %0, %1, %2, %3" : "=v"(d) : "v"(a), "v"(b), "v"(c));
  return d;
}

__device__ __forceinline__ float fast_exp2(float x) {
#if __has_builtin(__builtin_amdgcn_exp2f)
  return __builtin_amdgcn_exp2f(x);
#else
  return exp2f(x);
#endif
}

__device__ __forceinline__ int pack4i8(float a, float b, float c, float d) {
  int ia = (int)rintf(a), ib = (int)rintf(b), ic = (int)rintf(c), id = (int)rintf(d);
  return (ia & 255) | ((ib & 255) << 8) | ((ic & 255) << 16) | (id << 24);
}

// async global->LDS, 16B/lane, wave-uniform LDS base + lane*16 (linear dest).
typedef __attribute__((address_space(1))) void gas_void;
typedef __attribute__((address_space(3))) void las_void;
__device__ __forceinline__ void gll16(const void* g, void* l, int lane) {
#if __has_builtin(__builtin_amdgcn_global_load_lds)
  __builtin_amdgcn_global_load_lds((gas_void*)g, (las_void*)l, 16, 0, 0);
#else
  ((int4*)l)[lane] = *(const int4*)g;
#endif
}

// ---------------- amax: x + 4 weights in one dispatch ----------------
__device__ __forceinline__ void amax_reduce_store(float m, unsigned* slot) {
  __shared__ float wred[4];
  int wv = threadIdx.x >> 6, lane = threadIdx.x & 63;
#pragma unroll
  for (int off = 32; off > 0; off >>= 1) m = fmaxf(m, __shfl_down(m, off));
  if (lane == 0) wred[wv] = m;
  __syncthreads();
  if (threadIdx.x == 0) {
    float r = fmaxf(fmaxf(wred[0], wred[1]), fmaxf(wred[2], wred[3]));
    atomicMax(slot, __float_as_uint(r));
  }
}

__global__ __launch_bounds__(256) void amax5_kernel(
    const float* __restrict__ x, const float* w0, const float* w1,
    const float* w2, const float* w3, int n4x, int n4w,
    unsigned* __restrict__ slots) {
  int y = blockIdx.y;
  const float* p = (y == 0) ? x : (y == 1) ? w0 : (y == 2) ? w1 : (y == 3) ? w2 : w3;
  int n4 = (y == 0) ? n4x : n4w;
  const float4* x4 = (const float4*)p;
  float m = 0.f;
  for (int i = blockIdx.x * blockDim.x + threadIdx.x; i < n4; i += gridDim.x * blockDim.x) {
    float4 v = x4[i];
    m = fmaxf(m, fmaxf(fmaxf(fabsf(v.x), fabsf(v.y)), fmaxf(fabsf(v.z), fabsf(v.w))));
  }
  amax_reduce_store(m, slots + y);
}

// ------- fused prep: 4 rows/block act-quant + LoRA-t, weight-quant tail -------
__global__ __launch_bounds__(256) void prep_kernel(
    const float* __restrict__ x, const unsigned* __restrict__ slots,
    i8_t* __restrict__ xc,
    const float* __restrict__ A0, const float* __restrict__ A1, const float* __restrict__ A2,
    float* __restrict__ t0, float* __restrict__ t1, float* __restrict__ t2,
    const float* w0, const float* w1, const float* w2, const float* w3,
    i8_t* q0, i8_t* q1, i8_t* q2, i8_t* q3, int n4w) {
  const int tid = threadIdx.x;
  if ((int)blockIdx.x >= MROWS / 4) {
    int wb = blockIdx.x - MROWS / 4;
    int y = wb >> 7, bx = wb & 127;
    const float* wsrc = (y == 0) ? w0 : (y == 1) ? w1 : (y == 2) ? w2 : w3;
    i8_t* qc = (y == 0) ? q0 : (y == 1) ? q1 : (y == 2) ? q2 : q3;
    float amax = __uint_as_float(slots[y + 1]);
    float inv = 1.0f / fmaxf(amax / 127.0f, 1e-8f);
    const float4* x4 = (const float4*)wsrc;
    int* q4 = (int*)qc;
    for (int i = bx * 256 + tid; i < n4w; i += 128 * 256) {
      float4 v = x4[i];
      q4[i] = pack4i8(v.x * inv, v.y * inv, v.z * inv, v.w * inv);
    }
    return;
  }
  const int row0 = blockIdx.x * 4;
  const int k0 = tid * 4;
  float amax = __uint_as_float(slots[0]);
  float inv = 1.0f / fmaxf(amax / 127.0f, 1e-8f);

  float4 xv[4];
#pragma unroll
  for (int rr = 0; rr < 4; rr++) {
    xv[rr] = *(const float4*)&x[(size_t)(row0 + rr) * DIM + k0];
    *(int*)&xc[(size_t)(row0 + rr) * DIM + k0] =
        pack4i8(xv[rr].x * inv, xv[rr].y * inv, xv[rr].z * inv, xv[rr].w * inv);
  }

  float p[4][24];
#pragma unroll
  for (int r = 0; r < 8; r++) {
    float4 a0 = *(const float4*)&A0[r * DIM + k0];
    float4 a1 = *(const float4*)&A1[r * DIM + k0];
    float4 a2 = *(const float4*)&A2[r * DIM + k0];
#pragma unroll
    for (int rr = 0; rr < 4; rr++) {
      p[rr][r]      = xv[rr].x * a0.x + xv[rr].y * a0.y + xv[rr].z * a0.z + xv[rr].w * a0.w;
      p[rr][8 + r]  = xv[rr].x * a1.x + xv[rr].y * a1.y + xv[rr].z * a1.z + xv[rr].w * a1.w;
      p[rr][16 + r] = xv[rr].x * a2.x + xv[rr].y * a2.y + xv[rr].z * a2.z + xv[rr].w * a2.w;
    }
  }
#pragma unroll
  for (int rr = 0; rr < 4; rr++)
#pragma unroll
    for (int j = 0; j < 24; j++) {
      float v = p[rr][j];
#pragma unroll
      for (int off = 32; off > 0; off >>= 1) v += __shfl_down(v, off);
      p[rr][j] = v;
    }
  __shared__ float red[4][4][24];
  int wv = tid >> 6, lane = tid & 63;
  if (lane == 0) {
#pragma unroll
    for (int rr = 0; rr < 4; rr++)
#pragma unroll
      for (int j = 0; j < 24; j++) red[wv][rr][j] = p[rr][j];
  }
  __syncthreads();
  if (tid < 96) {
    int rr = tid / 24, j = tid - rr * 24;
    float sv = red[0][rr][j] + red[1][rr][j] + red[2][rr][j] + red[3][rr][j];
    float* tp = (j < 8) ? t0 : ((j < 16) ? t1 : t2);
    tp[(size_t)(row0 + rr) * 8 + (j & 7)] = sv;
  }
}

// ------- act-quant + LoRA-t for attn output (bf16 input), 4 rows/block -------
__global__ __launch_bounds__(256) void lora_quant1_kernel(
    const ushort_t* __restrict__ x, const unsigned* __restrict__ slot,
    i8_t* __restrict__ xc, const float* __restrict__ A0, float* __restrict__ t0) {
  const int row0 = blockIdx.x * 4;
  const int tid = threadIdx.x;
  const int k0 = tid * 4;
  float amax = __uint_as_float(*slot);
  float inv = 1.0f / fmaxf(amax / 127.0f, 1e-8f);

  float4 xv[4];
#pragma unroll
  for (int rr = 0; rr < 4; rr++) {
    ushort4 xu = *(const ushort4*)&x[(size_t)(row0 + rr) * DIM + k0];
    xv[rr].x = bf2f(xu.x); xv[rr].y = bf2f(xu.y); xv[rr].z = bf2f(xu.z); xv[rr].w = bf2f(xu.w);
    *(int*)&xc[(size_t)(row0 + rr) * DIM + k0] =
        pack4i8(xv[rr].x * inv, xv[rr].y * inv, xv[rr].z * inv, xv[rr].w * inv);
  }

  float p[4][8];
#pragma unroll
  for (int r = 0; r < 8; r++) {
    float4 a = *(const float4*)&A0[r * DIM + k0];
#pragma unroll
    for (int rr = 0; rr < 4; rr++)
      p[rr][r] = xv[rr].x * a.x + xv[rr].y * a.y + xv[rr].z * a.z + xv[rr].w * a.w;
  }
#pragma unroll
  for (int rr = 0; rr < 4; rr++)
#pragma unroll
    for (int j = 0; j < 8; j++) {
      float v = p[rr][j];
#pragma unroll
      for (int off = 32; off > 0; off >>= 1) v += __shfl_down(v, off);
      p[rr][j] = v;
    }
  __shared__ float red[4][4][8];
  int wv = tid >> 6, lane = tid & 63;
  if (lane == 0) {
#pragma unroll
    for (int rr = 0; rr < 4; rr++)
#pragma unroll
      for (int j = 0; j < 8; j++) red[wv][rr][j] = p[rr][j];
  }
  __syncthreads();
  if (tid < 32) {
    int rr = tid >> 3, j = tid & 7;
    t0[(size_t)(row0 + rr) * 8 + j] =
        red[0][rr][j] + red[1][rr][j] + red[2][rr][j] + red[3][rr][j];
  }
}

// ------- projection GEMM on int8 codes via mfma_i32_16x16x64_i8 (exact) -------
template <bool BF16OUT, int BN, bool CANTRANS>
__device__ __forceinline__ void proj_body(
    const i8_t* __restrict__ Ac, const i8_t* __restrict__ Wc,
    const unsigned* __restrict__ sxslot, const unsigned* __restrict__ swslot,
    const float* __restrict__ bias, const float* __restrict__ t,
    const float* __restrict__ Bl, void* __restrict__ Cout,
    ushort_t* __restrict__ vTout, int m0, int n0) {
  constexpr int CODEB = 128 * 128 + BN * 128;
  constexpr int T2B = CANTRANS ? 128 * 136 * 2 : 0;
  constexpr int BASE = (T2B > CODEB) ? T2B : CODEB;
  __shared__ alignas(16) char smem[BASE + 128 * 32 + BN * 32 + BN * 4];
  i8_t* Asb = (i8_t*)smem;
  i8_t* Bsb = (i8_t*)(smem + 128 * 128);
  ushort_t* T2 = (ushort_t*)smem;
  float* Ts = (float*)(smem + BASE);
  float* Bls = Ts + 128 * 8;
  float* biass = Bls + BN * 8;

  const int tid = threadIdx.x;
  constexpr int NJ = BN / 32;
  constexpr int BITS = BN / 32;

  for (int i = tid; i < 128 * 8; i += 256) Ts[i] = t[(size_t)m0 * 8 + i];
  for (int i = tid; i < BN * 8; i += 256) Bls[i] = Bl[(size_t)n0 * 8 + i];
  if (tid < BN) biass[tid] = bias[n0 + tid];

  int32x4 acc[4][NJ];
#pragma unroll
  for (int i = 0; i < 4; i++)
#pragma unroll
    for (int j = 0; j < NJ; j++) {
      acc[i][j][0] = 0; acc[i][j][1] = 0; acc[i][j][2] = 0; acc[i][j][3] = 0;
    }

  const int wv = tid >> 6, lane = tid & 63;
  const int wr = wv >> 1, wc = wv & 1;
  const int l15 = lane & 15, hi = lane >> 4;
  const int lr8 = lane >> 3, lc8 = lane & 7;

  for (int kt = 0; kt < 8; kt++) {
    const int k0 = kt * 128;
#pragma unroll
    for (int j = 0; j < 4; j++) {
      int row = wv * 32 + j * 8 + lr8;
      int cs = lc8 ^ (row & 7);
      gll16(&Ac[(size_t)(m0 + row) * DIM + k0 + cs * 16], &Asb[(wv * 32 + j * 8) * 128], lane);
    }
#pragma unroll
    for (int j = 0; j < BITS; j++) {
      int row = wv * (BN / 4) + j * 8 + lr8;
      int cs = lc8 ^ (row & 7);
      gll16(&Wc[(size_t)(n0 + row) * DIM + k0 + cs * 16], &Bsb[(wv * (BN / 4) + j * 8) * 128], lane);
    }
    __syncthreads();
#pragma unroll
    for (int ks = 0; ks < 2; ks++) {
      int32x4 a[4], b[NJ];
#pragma unroll
      for (int i = 0; i < 4; i++) {
        int row = wr * 64 + i * 16 + l15;
        a[i] = *(const int32x4*)&Asb[row * 128 + (((ks * 4 + hi) ^ (row & 7))) * 16];
      }
#pragma unroll
      for (int j = 0; j < NJ; j++) {
        int col = wc * (BN / 2) + j * 16 + l15;
        b[j] = *(const int32x4*)&Bsb[col * 128 + (((ks * 4 + hi) ^ (col & 7))) * 16];
      }
      __builtin_amdgcn_s_setprio(1);
#pragma unroll
      for (int i = 0; i < 4; i++)
#pragma unroll
        for (int j = 0; j < NJ; j++)
          acc[i][j] = __builtin_amdgcn_mfma_i32_16x16x64_i8(a[i], b[j], acc[i][j], 0, 0, 0);
      __builtin_amdgcn_s_setprio(0);
    }
    __syncthreads();
  }

  float sx = fmaxf(__uint_as_float(*sxslot) / 127.0f, 1e-8f);
  float sw = fmaxf(__uint_as_float(*swslot) / 127.0f, 1e-8f);
  float ss = sx * sw;

  if (CANTRANS && vTout != nullptr) {
#pragma unroll
    for (int i = 0; i < 4; i++) {
      int rl0 = wr * 64 + i * 16 + hi * 4;
      float tv[4][8];
#pragma unroll
      for (int rr = 0; rr < 4; rr++)
#pragma unroll
        for (int q = 0; q < 8; q++) tv[rr][q] = Ts[(rl0 + rr) * 8 + q];
#pragma unroll
      for (int j = 0; j < NJ; j++) {
        int cl = wc * (BN / 2) + j * 16 + l15;
        float val[4];
#pragma unroll
        for (int rr = 0; rr < 4; rr++) {
          float lr = 0.f;
#pragma unroll
          for (int q = 0; q < 8; q++) lr += tv[rr][q] * Bls[cl * 8 + q];
          val[rr] = (float)acc[i][j][rr] * ss + biass[cl] + 2.0f * lr;
        }
        unsigned w0 = cvt_pk_bf16(val[0], val[1]);
        unsigned w1 = cvt_pk_bf16(val[2], val[3]);
        *(uint2*)&T2[cl * 136 + rl0] = make_uint2(w0, w1);
      }
    }
    __syncthreads();
    const int bb = m0 >> 11;
    const int sbase = m0 & 2047;
#pragma unroll
    for (int it = 0; it < 8; it++) {
      int g = it * 256 + tid;
      int d = g >> 4, c = g & 15;
      int gdim = n0 + d;
      int hh = gdim >> 6, dd = gdim & 63;
      int bh = bb * 16 + hh;
      int4 v = *(const int4*)&T2[d * 136 + c * 8];
      *(int4*)&vTout[((size_t)(bh * 64 + dd)) * SEQ + sbase + c * 8] = v;
    }
    return;
  }

#pragma unroll
  for (int i = 0; i < 4; i++) {
#pragma unroll
    for (int rr = 0; rr < 4; rr++) {
      int rl = wr * 64 + i * 16 + hi * 4 + rr;
      float tv[8];
#pragma unroll
      for (int q = 0; q < 8; q++) tv[q] = Ts[rl * 8 + q];
#pragma unroll
      for (int j = 0; j < NJ; j++) {
        int cl = wc * (BN / 2) + j * 16 + l15;
        float lr = 0.f;
#pragma unroll
        for (int q = 0; q < 8; q++) lr += tv[q] * Bls[cl * 8 + q];
        float val = (float)acc[i][j][rr] * ss + biass[cl] + 2.0f * lr;
        if (BF16OUT)
          ((ushort_t*)Cout)[(size_t)(m0 + rl) * DIM + n0 + cl] = f2bf(val);
        else
          ((float*)Cout)[(size_t)(m0 + rl) * DIM + n0 + cl] = val;
      }
    }
  }
}

struct ProjSet {
  const i8_t* W; const unsigned* sw; const float* bias;
  const float* t; const float* Bl; ushort_t* out;
};

__global__ __launch_bounds__(256) void proj_qkv_kernel(
    const i8_t* __restrict__ Ac, const unsigned* __restrict__ sxslot,
    ProjSet pq, ProjSet pk, ProjSet pv, ushort_t* __restrict__ vT) {
  ProjSet P = (blockIdx.z == 0) ? pq : (blockIdx.z == 1) ? pk : pv;
  ushort_t* vt = (blockIdx.z == 2) ? vT : nullptr;
  proj_body<true, 128, true>(Ac, P.W, sxslot, P.sw, P.bias, P.t, P.Bl, P.out,
                             vt, blockIdx.y * 128, blockIdx.x * 128);
}

__global__ __launch_bounds__(256) void proj_out_kernel(
    const i8_t* __restrict__ Ac, const i8_t* __restrict__ Wc,
    const unsigned* __restrict__ sxslot, const unsigned* __restrict__ swslot,
    const float* __restrict__ bias, const float* __restrict__ t,
    const float* __restrict__ Bl, float* __restrict__ Cout) {
  proj_body<false, 64, false>(Ac, Wc, sxslot, swslot, bias, t, Bl, Cout,
                              nullptr, blockIdx.y * 128, blockIdx.x * 64);
}

// ------- flash attention v12: attn10 + ls-as-MFMA-accumulator + max3 rowmax -------
__global__ __launch_bounds__(512) void attn12_kernel(
    const ushort_t* __restrict__ qb, const ushort_t* __restrict__ kb,
    const ushort_t* __restrict__ vT, const float* __restrict__ mask,
    ushort_t* __restrict__ obuf, unsigned* __restrict__ amax_slot) {
  __shared__ alignas(16) ushort_t Ks[2][64 * 64];
  __shared__ alignas(16) ushort_t Vs[2][64 * 64];   // Vs[d][key]
  __shared__ alignas(16) ushort_t Ps[128 * 72];
  __shared__ alignas(16) float maskv[2][64];
  __shared__ float wmax[8];

  const float LOG2E = 1.44269504088896f;
  const float SCL2 = 0.125f * LOG2E;
  const float THR2 = 8.0f * LOG2E;

  const int lin = blockIdx.x;
  const int logical = (lin & 7) * 64 + (lin >> 3);
  const int bh = logical >> 4;
  const int qt = logical & 15;
  const int b = bh >> 4, h = bh & 15;
  const size_t tokbase = (size_t)b * SEQ;
  const int q0 = qt * 128;

  const int tid = threadIdx.x;
  const int wv = tid >> 6, lane = tid & 63, l15 = lane & 15, hi = lane >> 4;
  const int sr = tid >> 3, sc = tid & 7;
  const int sslot = (sc ^ (sr & 7)) * 8;

  // all-ones bf16 fragment (1.0 = 0x3F80)
  const short8 ones8 = {0x3F80, 0x3F80, 0x3F80, 0x3F80, 0x3F80, 0x3F80, 0x3F80, 0x3F80};

  short8 qf[2];
#pragma unroll
  for (int ks = 0; ks < 2; ks++) {
    int row = q0 + wv * 16 + l15;
    qf[ks] = *(const short8*)&qb[(tokbase + row) * DIM + h * 64 + ks * 32 + hi * 8];
  }

  float mo = -1e30f;
  f32x4 o[4], o5;   // o5 = row-sum accumulator (P @ ones)
#pragma unroll
  for (int d = 0; d < 4; d++) { o[d][0] = 0.f; o[d][1] = 0.f; o[d][2] = 0.f; o[d][3] = 0.f; }
  o5[0] = 0.f; o5[1] = 0.f; o5[2] = 0.f; o5[3] = 0.f;

  int4 kpre, vpre;
  float mpre;
  kpre = *(const int4*)&kb[(tokbase + sr) * DIM + h * 64 + sc * 8];
  vpre = *(const int4*)&vT[((size_t)bh * 64 + sr) * SEQ + sc * 8];
  mpre = (tid < 64) ? (1.0f - mask[tokbase + tid]) * (-10000.0f * LOG2E) : 0.f;
  *(int4*)&Ks[0][sr * 64 + sslot] = kpre;
  *(int4*)&Vs[0][sr * 64 + sslot] = vpre;
  if (tid < 64) maskv[0][tid] = mpre;
  __syncthreads();

  for (int kt = 0; kt < 32; kt++) {
    const int cur = kt & 1, nxt = cur ^ 1;

    if (kt < 31) {
      const int k0n = (kt + 1) * 64;
      kpre = *(const int4*)&kb[(tokbase + k0n + sr) * DIM + h * 64 + sc * 8];
      vpre = *(const int4*)&vT[((size_t)bh * 64 + sr) * SEQ + k0n + sc * 8];
      if (tid < 64) mpre = (1.0f - mask[tokbase + k0n + tid]) * (-10000.0f * LOG2E);
    }

    // S^T = K Q^T
    f32x4 s2[4];
#pragma unroll
    for (int kb4 = 0; kb4 < 4; kb4++) { s2[kb4][0] = 0.f; s2[kb4][1] = 0.f; s2[kb4][2] = 0.f; s2[kb4][3] = 0.f; }
#pragma unroll
    for (int ks = 0; ks < 2; ks++) {
      short8 kf[4];
#pragma unroll
      for (int kb4 = 0; kb4 < 4; kb4++) {
        int row = kb4 * 16 + l15;
        kf[kb4] = *(const short8*)&Ks[cur][row * 64 + (((ks * 4 + hi) ^ (row & 7))) * 8];
      }
      __builtin_amdgcn_s_setprio(1);
#pragma unroll
      for (int kb4 = 0; kb4 < 4; kb4++)
        s2[kb4] = __builtin_amdgcn_mfma_f32_16x16x32_bf16(kf[kb4], qf[ks], s2[kb4], 0, 0, 0);
      __builtin_amdgcn_s_setprio(0);
    }

    // mask + scale
#pragma unroll
    for (int kb4 = 0; kb4 < 4; kb4++) {
      f32x4 mkv = *(const f32x4*)&maskv[cur][kb4 * 16 + hi * 4];
#pragma unroll
      for (int r = 0; r < 4; r++)
        s2[kb4][r] = s2[kb4][r] * SCL2 + mkv[r];
    }

    // row-max via v_max3 + 2-step cross shfl
    float m1 = max3f(s2[0][0], s2[0][1], s2[0][2]);
    float m2 = max3f(s2[0][3], s2[1][0], s2[1][1]);
    float m3 = max3f(s2[1][2], s2[1][3], s2[2][0]);
    float m4 = max3f(s2[2][1], s2[2][2], s2[2][3]);
    float m5 = max3f(s2[3][0], s2[3][1], s2[3][2]);
    float tm = fmaxf(max3f(m1, m2, m3), max3f(m4, m5, s2[3][3]));
    tm = fmaxf(tm, __shfl_xor(tm, 16));
    tm = fmaxf(tm, __shfl_xor(tm, 32));

    // defer-max (T13)
    bool need = (tm > mo + THR2);
    if (__any(need)) {
      float mn = fmaxf(mo, tm);
      float al = fast_exp2(mo - mn);
      mo = mn;
#pragma unroll
      for (int r = 0; r < 4; r++) {
        float ab = __shfl(al, hi * 4 + r);
#pragma unroll
        for (int db = 0; db < 4; db++) o[db][r] *= ab;
        o5[r] *= ab;
      }
    }

    // exp (row-sum now rides the matrix pipe via o5)
#pragma unroll
    for (int kb4 = 0; kb4 < 4; kb4++)
#pragma unroll
      for (int r = 0; r < 4; r++)
        s2[kb4][r] = fast_exp2(s2[kb4][r] - mo);

    // P -> LDS (wave-private rows wv*16 + l15)
    {
      int rowb = (wv * 16 + l15) * 72;
#pragma unroll
      for (int kb4 = 0; kb4 < 4; kb4++) {
        unsigned w0 = cvt_pk_bf16(s2[kb4][0], s2[kb4][1]);
        unsigned w1 = cvt_pk_bf16(s2[kb4][2], s2[kb4][3]);
        *(uint2*)&Ps[rowb + kb4 * 16 + hi * 4] = make_uint2(w0, w1);
      }
    }

    // O += P V ; o5 += P @ ones (row sums)
#pragma unroll
    for (int ks = 0; ks < 2; ks++) {
      short8 pf = *(const short8*)&Ps[(wv * 16 + l15) * 72 + ks * 32 + hi * 8];
      short8 vf[4];
#pragma unroll
      for (int db = 0; db < 4; db++) {
        int row = db * 16 + l15;
        vf[db] = *(const short8*)&Vs[cur][row * 64 + (((ks * 4 + hi) ^ (row & 7))) * 8];
      }
      __builtin_amdgcn_s_setprio(1);
#pragma unroll
      for (int db = 0; db < 4; db++)
        o[db] = __builtin_amdgcn_mfma_f32_16x16x32_bf16(pf, vf[db], o[db], 0, 0, 0);
      o5 = __builtin_amdgcn_mfma_f32_16x16x32_bf16(pf, ones8, o5, 0, 0, 0);
      __builtin_amdgcn_s_setprio(0);
    }

    if (kt < 31) {
      *(int4*)&Ks[nxt][sr * 64 + sslot] = kpre;
      *(int4*)&Vs[nxt][sr * 64 + sslot] = vpre;
      if (tid < 64) maskv[nxt][tid] = mpre;
    }
    __syncthreads();
  }

  // epilogue: ls = o5[r] in-lane (no shfl); bf16 output; amax on rounded values
  float am = 0.f;
#pragma unroll
  for (int r = 0; r < 4; r++) {
    float inv = 1.0f / o5[r];
    size_t row = tokbase + q0 + wv * 16 + hi * 4 + r;
#pragma unroll
    for (int db = 0; db < 4; db++) {
      float val = o[db][r] * inv;
      ushort_t bv = f2bf(val);
      am = fmaxf(am, fabsf(bf2f(bv)));
      obuf[row * DIM + h * 64 + db * 16 + l15] = bv;
    }
  }
#pragma unroll
  for (int off = 32; off > 0; off >>= 1) am = fmaxf(am, __shfl_down(am, off));
  if (lane == 0) wmax[wv] = am;
  __syncthreads();
  if (tid == 0) {
    float r = wmax[0];
#pragma unroll
    for (int w = 1; w < 8; w++) r = fmaxf(r, wmax[w]);
    atomicMax(amax_slot, __float_as_uint(r));
  }
}

// ---------------- launcher ----------------
extern "C" void kernel_launch(void* const* d_in, const int* in_sizes, int n_in,
                              void* d_out, int out_size, void* d_ws, size_t ws_size,
                              hipStream_t stream) {
  const float* x     = (const float*)d_in[0];
  const float* mask  = (const float*)d_in[1];
  const float* q_W   = (const float*)d_in[2];
  const float* q_b   = (const float*)d_in[3];
  const float* q_A   = (const float*)d_in[4];
  const float* q_B   = (const float*)d_in[5];
  const float* k_W   = (const float*)d_in[6];
  const float* k_b   = (const float*)d_in[7];
  const float* k_A   = (const float*)d_in[8];
  const float* k_B   = (const float*)d_in[9];
  const float* v_W   = (const float*)d_in[10];
  const float* v_b   = (const float*)d_in[11];
  const float* v_A   = (const float*)d_in[12];
  const float* v_B   = (const float*)d_in[13];
  const float* o_W   = (const float*)d_in[14];
  const float* o_b   = (const float*)d_in[15];
  const float* o_A   = (const float*)d_in[16];
  const float* o_B   = (const float*)d_in[17];
  float* out = (float*)d_out;

  char* ws = (char*)d_ws;
  const size_t MB = 1u << 20;
  unsigned* slots = (unsigned*)ws;                  // 6 amax slots
  float* t_q = (float*)(ws + 4096);
  float* t_k = t_q + MROWS * 8;
  float* t_v = t_k + MROWS * 8;
  float* t_o = t_v + MROWS * 8;
  i8_t* xc  = (i8_t*)(ws + 1 * MB);
  i8_t* qWc = (i8_t*)(ws + 9 * MB);
  i8_t* kWc = (i8_t*)(ws + 11 * MB);
  i8_t* vWc = (i8_t*)(ws + 13 * MB);
  i8_t* oWc = (i8_t*)(ws + 15 * MB);
  ushort_t* qbb = (ushort_t*)(ws + 17 * MB);
  ushort_t* kbb = (ushort_t*)(ws + 25 * MB);
  ushort_t* vTb = (ushort_t*)(ws + 41 * MB);
  ushort_t* abuf = (ushort_t*)(ws + 49 * MB);
  i8_t*     ac  = (i8_t*)(ws + 65 * MB);

  (void)hipMemsetAsync(ws, 0, 64, stream);

  const int NX4 = (MROWS * DIM) / 4;
  const int NW4 = (DIM * DIM) / 4;

  amax5_kernel<<<dim3(256, 5), 256, 0, stream>>>(x, q_W, k_W, v_W, o_W, NX4, NW4, slots);

  prep_kernel<<<MROWS / 4 + 512, 256, 0, stream>>>(x, slots, xc, q_A, k_A, v_A,
                                                   t_q, t_k, t_v,
                                                   q_W, k_W, v_W, o_W,
                                                   qWc, kWc, vWc, oWc, NW4);

  ProjSet pq = { qWc, slots + 1, q_b, t_q, q_B, qbb };
  ProjSet pk = { kWc, slots + 2, k_b, t_k, k_B, kbb };
  ProjSet pv = { vWc, slots + 3, v_b, t_v, v_B, nullptr };
  proj_qkv_kernel<<<dim3(DIM / 128, MROWS / 128, 3), 256, 0, stream>>>(
      xc, slots + 0, pq, pk, pv, vTb);

  attn12_kernel<<<512, 512, 0, stream>>>(qbb, kbb, vTb, mask, abuf, slots + 5);

  lora_quant1_kernel<<<MROWS / 4, 256, 0, stream>>>(abuf, slots + 5, ac, o_A, t_o);

  proj_out_kernel<<<dim3(DIM / 64, MROWS / 128), 256, 0, stream>>>(
      ac, oWc, slots + 5, slots + 4, o_b, t_o, o_B, out);
}